// Round 2
// baseline (270.439 us; speedup 1.0000x reference)
//
#include <hip/hip_runtime.h>

typedef __bf16 bf16x8 __attribute__((ext_vector_type(8)));
typedef float f32x4 __attribute__((ext_vector_type(4)));

#define B_ 4
#define T_ 2048
#define D_ 1024
#define H_ 16
#define HD_ 64
#define M_ 8192
// 1/sqrt(64) * log2(e), folded into Q so softmax uses exp2
#define QSCALE 0.1803368801111204f

__device__ __forceinline__ ushort f2b(float f) {
  union { float f; unsigned u; } v; v.f = f;
  unsigned u = v.u;
  return (ushort)((u + 0x7FFFu + ((u >> 16) & 1u)) >> 16);
}

// pack two floats to bf16 pair (round-half-up: +0x8000 then take hi16)
__device__ __forceinline__ unsigned pkbf(float a, float b) {
  union { float f; unsigned u; } va, vb; va.f = a; vb.f = b;
  return __builtin_amdgcn_perm(vb.u + 0x8000u, va.u + 0x8000u, 0x07060302u);
}

// async global->LDS, 16B per lane. LDS dest must be wave-uniform base + lane*16.
__device__ __forceinline__ void gll16(const void* g, void* l) {
  __builtin_amdgcn_global_load_lds(
      (const __attribute__((address_space(1))) unsigned*)g,
      (__attribute__((address_space(3))) unsigned*)l, 16, 0, 0);
}

__global__ __launch_bounds__(256) void cast_x_kernel(const float* __restrict__ x,
                                                     ushort* __restrict__ xb) {
  int idx = blockIdx.x * 256 + threadIdx.x;
  float4 v = ((const float4*)x)[idx];
  ushort4 o;
  o.x = f2b(v.x); o.y = f2b(v.y); o.z = f2b(v.z); o.w = f2b(v.w);
  ((ushort4*)xb)[idx] = o;
}

// 32x32 tiled transpose+cast: dst[n][k] = src[k][n], bf16 out
__global__ __launch_bounds__(256) void transpose_w_kernel(
    const float* __restrict__ wq, const float* __restrict__ wk,
    const float* __restrict__ wv, const float* __restrict__ wo,
    ushort* __restrict__ wt_qkv, ushort* __restrict__ wt_o) {
  __shared__ float tile[32][33];
  int z = blockIdx.z;
  const float* src = (z == 0) ? wq : (z == 1) ? wk : (z == 2) ? wv : wo;
  ushort* dst = (z < 3) ? (wt_qkv + (size_t)z * D_ * D_) : wt_o;
  int n0 = blockIdx.x * 32, k0 = blockIdx.y * 32;
  int tx = threadIdx.x & 31, ty = threadIdx.x >> 5;
  for (int i = 0; i < 4; i++) {
    int r = ty + i * 8;
    tile[r][tx] = src[(size_t)(k0 + r) * D_ + n0 + tx];
  }
  __syncthreads();
  for (int i = 0; i < 4; i++) {
    int r = ty + i * 8;
    dst[(size_t)(n0 + r) * D_ + k0 + tx] = f2b(tile[tx][r]);
  }
}

// C = A(MxK) * Bt(NxK)^T, 128x128 tile, BK=64, bf16 MFMA 16x16x32.
// m97 structure: double-buffered LDS filled via global_load_lds dwordx4,
// single barrier per K-step, both-sides chunk swizzle. This round: XCD-chunked
// block remap so each XCD works a contiguous slab of the grid (A-panel +
// B-panels L2-resident).
__global__ __launch_bounds__(256) void gemm_kernel(
    const ushort* __restrict__ A, const ushort* __restrict__ Bt, int mode,
    const float* __restrict__ bias_q, const float* __restrict__ bias_k,
    const float* __restrict__ bias_v,
    ushort* __restrict__ qb, ushort* __restrict__ kb, ushort* __restrict__ vtb,
    float* __restrict__ outf) {
  __shared__ ushort As[2][128][64];  // 32 KB
  __shared__ ushort Bs[2][128][64];  // 32 KB
  int tid = threadIdx.x;
  int wave = tid >> 6, lane = tid & 63, lrow = lane >> 4, lcol = lane & 15;

  // XCD-chunked remap: consecutive HW blocks round-robin XCDs; give each XCD
  // a contiguous chunk of work-space. nwg = 1536 (mode0) / 512 (mode1), %8==0.
  int gx = gridDim.x;
  int nwg = gx * gridDim.y;
  int orig = blockIdx.x + gx * blockIdx.y;
  int work = (orig & 7) * (nwg >> 3) + (orig >> 3);
  int m0 = (work / gx) * 128, n0 = (work % gx) * 128;
  int wm = (wave & 1) * 64, wn = (wave >> 1) * 64;

  int rb = tid >> 3;            // 0..31
  int dc = tid & 7;             // dest 16B chunk
  int scv = dc ^ (rb & 7);      // swizzled source chunk
  const ushort* aBase = A + (size_t)(m0 + rb) * D_ + scv * 8;
  const ushort* bBase = Bt + (size_t)(n0 + rb) * D_ + scv * 8;

  f32x4 zero = {0.f, 0.f, 0.f, 0.f};
  f32x4 acc[4][4];
  for (int i = 0; i < 4; i++)
    for (int j = 0; j < 4; j++) acc[i][j] = zero;

  int swz = lcol & 7;

  auto stage = [&](int buf, int k) {
#pragma unroll
    for (int g = 0; g < 4; g++) {
      gll16(aBase + (size_t)(32 * g) * D_ + k, &As[buf][0][0] + tid * 8 + g * 2048);
      gll16(bBase + (size_t)(32 * g) * D_ + k, &Bs[buf][0][0] + tid * 8 + g * 2048);
    }
  };

  stage(0, 0);  // prologue

  for (int k0 = 0; k0 < D_; k0 += 64) {
    int cur = (k0 >> 6) & 1, nxt = cur ^ 1;
    __syncthreads();  // drains vmcnt -> buf[cur] ready; prior reads of nxt done
    if (k0 + 64 < D_) stage(nxt, k0 + 64);  // async, in flight across compute

    for (int ks = 0; ks < 2; ks++) {
      bf16x8 af[4], bf[4];
      int ch = ((ks * 4 + lrow) ^ swz) * 8;
      for (int mt = 0; mt < 4; mt++)
        af[mt] = *(const bf16x8*)&As[cur][wm + mt * 16 + lcol][ch];
      for (int nt = 0; nt < 4; nt++)
        bf[nt] = *(const bf16x8*)&Bs[cur][wn + nt * 16 + lcol][ch];
      for (int mt = 0; mt < 4; mt++)
        for (int nt = 0; nt < 4; nt++)
          acc[mt][nt] = __builtin_amdgcn_mfma_f32_16x16x32_bf16(
              af[mt], bf[nt], acc[mt][nt], 0, 0, 0);
    }
  }

  if (mode == 0) {
    int proj = n0 >> 10;  // uniform per block (128 | 1024)
    const float* bias = (proj == 0) ? bias_q : (proj == 1) ? bias_k : bias_v;
    for (int mt = 0; mt < 4; mt++) {
      int gm0 = m0 + wm + mt * 16 + lrow * 4;  // 4 consecutive t, same b
      int b = gm0 >> 11, tp = gm0 & 2047;
      for (int nt = 0; nt < 4; nt++) {
        int gn = n0 + wn + nt * 16 + lcol;
        int inner = gn & 1023;
        int h = inner >> 6, hd = inner & 63;
        float bv = bias[inner];
        if (proj == 0) {
          size_t base = ((size_t)(b * H_ + h) * T_ + tp) * HD_ + hd;
          for (int r = 0; r < 4; r++)
            qb[base + (size_t)r * HD_] = f2b((acc[mt][nt][r] + bv) * QSCALE);
        } else if (proj == 1) {
          size_t base = ((size_t)(b * H_ + h) * T_ + tp) * HD_ + hd;
          for (int r = 0; r < 4; r++)
            kb[base + (size_t)r * HD_] = f2b(acc[mt][nt][r] + bv);
        } else {  // V stored transposed: (B,H,HD,T); 4 t's pack into ushort4
          ushort4 pk;
          pk.x = f2b(acc[mt][nt][0] + bv);
          pk.y = f2b(acc[mt][nt][1] + bv);
          pk.z = f2b(acc[mt][nt][2] + bv);
          pk.w = f2b(acc[mt][nt][3] + bv);
          *(ushort4*)&vtb[((size_t)(b * H_ + h) * HD_ + hd) * T_ + tp] = pk;
        }
      }
    }
  } else {
    for (int mt = 0; mt < 4; mt++) {
      int gm0 = m0 + wm + mt * 16 + lrow * 4;
      for (int nt = 0; nt < 4; nt++) {
        int gn = n0 + wn + nt * 16 + lcol;
        float bv = bias_q[gn];
        for (int r = 0; r < 4; r++)
          outf[(size_t)(gm0 + r) * D_ + gn] = acc[mt][nt][r] + bv;
      }
    }
  }
}

// Causal flash attention, fixed-base softmax (log2-unit scores, exp2, no max
// subtraction — validated in prior rounds). Round-2 structure:
//  - 128-row q-tiles, 32 q per wave (two 16-q halves): 36 MFMA per staged
//    KV tile per wave (was 18), half the tile-iterations/staging/barriers.
//  - LDS stride reverted to 80 ushorts (160 B): empirically 6.49M conflicts
//    vs 11.9M at 72 (round-1 regression; the 144B stride is worse for this
//    access mix — model refuted, measurement kept).
//  - XCD remap kept (FETCH 195->24.6 MB in round 1): 8 bh per XCD.
//  - s_setprio(1) around MFMA clusters (T5, attn-positive m191).
//  - waves whose q-rows are entirely below a diagonal KV tile skip compute.
__global__ __launch_bounds__(256) void flash_kernel(
    const ushort* __restrict__ qb, const ushort* __restrict__ kb,
    const ushort* __restrict__ vtb, ushort* __restrict__ ob) {
  __shared__ ushort Ks[64][80];      // [kv][hd]
  __shared__ ushort Vs[64][80];      // [hd][kv]  (global V pre-transposed)
  __shared__ ushort Ps[4][32][80];   // per-wave P^T strip: [q][kv]
  int tid = threadIdx.x;
  int wave = tid >> 6, lane = tid & 63, lrow = lane >> 4, lcol = lane & 15;

  int bid = blockIdx.x + (blockIdx.y << 4);  // grid (16,64) -> 0..1023
  int xcd = bid & 7;                         // HW round-robin XCD id
  int slot = bid >> 3;                       // per-XCD sequence 0..127
  int bh = xcd * 8 + (slot >> 4);            // 8 bh per XCD -> K/V L2-resident
  int qblk = 15 - (slot & 15);               // heavy q-blocks dispatched first
  int b = bh >> 4, h = bh & 15;
  const ushort* qp = qb + (size_t)bh * T_ * HD_;
  const ushort* kh = kb + (size_t)bh * T_ * HD_;
  const ushort* vh = vtb + (size_t)bh * HD_ * T_;

  int r0 = tid >> 3, cb0 = (tid & 7) * 8;   // staging: row, col-chunk
  // prefetch KV tile j=0 into registers (named scalars; no-spill pattern)
  uint4 kr0 = *(const uint4*)&kh[(size_t)r0 * HD_ + cb0];
  uint4 kr1 = *(const uint4*)&kh[(size_t)(r0 + 32) * HD_ + cb0];
  uint4 vr0 = *(const uint4*)&vh[(size_t)r0 * T_ + cb0];
  uint4 vr1 = *(const uint4*)&vh[(size_t)(r0 + 32) * T_ + cb0];

  // constant ones-row A-fragment: A[m=0][*]=1, A[m>0][*]=0 (m = lcol)
  bf16x8 af1;
  {
    __bf16 ov = (__bf16)((lcol == 0) ? 1.0f : 0.0f);
    for (int i = 0; i < 8; i++) af1[i] = ov;
  }

  f32x4 zero = {0.f, 0.f, 0.f, 0.f};

  int q0w = qblk * 128 + wave * 32;  // wave's first q row (32 rows per wave)
  // Q as B-operand frags, two 16-q halves: [n=q=lcol][k=hd]
  bf16x8 qf[2][2];
#pragma unroll
  for (int qh = 0; qh < 2; qh++)
#pragma unroll
    for (int ks = 0; ks < 2; ks++)
      qf[qh][ks] = *(const bf16x8*)&qp[(size_t)(q0w + qh * 16 + lcol) * HD_ +
                                       ks * 32 + lrow * 8];

  f32x4 accO[2][4];  // O^T frags per q-half: rows=hd, cols=q=lcol
  f32x4 accS[2];     // ones-row accumulators: row 0 = per-q sum of P
#pragma unroll
  for (int qh = 0; qh < 2; qh++) {
    accS[qh] = zero;
    for (int mt = 0; mt < 4; mt++) accO[qh][mt] = zero;
  }

  int nj = qblk * 2 + 2;  // KV tiles 0 .. 2*qblk+1 (covers q0..q0+127)
  for (int j = 0; j < nj; j++) {
    __syncthreads();  // all waves done reading previous tile
    *(uint4*)&Ks[r0][cb0] = kr0;
    *(uint4*)&Ks[r0 + 32][cb0] = kr1;
    *(uint4*)&Vs[r0][cb0] = vr0;
    *(uint4*)&Vs[r0 + 32][cb0] = vr1;
    __syncthreads();

    // prefetch next tile
    if (j + 1 < nj) {
      int jn = j + 1;
      kr0 = *(const uint4*)&kh[(size_t)(jn * 64 + r0) * HD_ + cb0];
      kr1 = *(const uint4*)&kh[(size_t)(jn * 64 + r0 + 32) * HD_ + cb0];
      vr0 = *(const uint4*)&vh[(size_t)r0 * T_ + jn * 64 + cb0];
      vr1 = *(const uint4*)&vh[(size_t)(r0 + 32) * T_ + jn * 64 + cb0];
    }

    // wave-level skip: tile entirely above the causal boundary for this wave
    if (j * 64 > q0w + 31) continue;

    // S^T = K Q^T for both q-halves; K-frags loaded once, used twice
    f32x4 st[2][4];
#pragma unroll
    for (int qh = 0; qh < 2; qh++)
      for (int mt = 0; mt < 4; mt++) st[qh][mt] = zero;
    __builtin_amdgcn_s_setprio(1);
#pragma unroll
    for (int ks = 0; ks < 2; ks++)
#pragma unroll
      for (int mt = 0; mt < 4; mt++) {
        bf16x8 kf = *(const bf16x8*)&Ks[mt * 16 + lcol][ks * 32 + lrow * 8];
        st[0][mt] = __builtin_amdgcn_mfma_f32_16x16x32_bf16(kf, qf[0][ks], st[0][mt], 0, 0, 0);
        st[1][mt] = __builtin_amdgcn_mfma_f32_16x16x32_bf16(kf, qf[1][ks], st[1][mt], 0, 0, 0);
      }
    __builtin_amdgcn_s_setprio(0);

    if (j >= 2 * qblk) {  // diagonal region: causal mask (exact predicate)
#pragma unroll
      for (int qh = 0; qh < 2; qh++) {
        int q_g = q0w + qh * 16 + lcol;
#pragma unroll
        for (int mt = 0; mt < 4; mt++)
          for (int r = 0; r < 4; r++) {
            int kv_g = j * 64 + mt * 16 + lrow * 4 + r;
            if (kv_g > q_g) st[qh][mt][r] = -1e30f;
          }
      }
    }

    // fixed-base softmax numerator: P = exp2(S), no max, no rescale
#pragma unroll
    for (int qh = 0; qh < 2; qh++)
      for (int mt = 0; mt < 4; mt++)
        for (int r = 0; r < 4; r++)
          st[qh][mt][r] = __builtin_amdgcn_exp2f(st[qh][mt][r]);

    // P^T -> LDS (packed bf16 pairs; same-wave write->read)
#pragma unroll
    for (int qh = 0; qh < 2; qh++)
      for (int mt = 0; mt < 4; mt++) {
        uint2 pk;
        pk.x = pkbf(st[qh][mt][0], st[qh][mt][1]);
        pk.y = pkbf(st[qh][mt][2], st[qh][mt][3]);
        *(uint2*)&Ps[wave][qh * 16 + lcol][mt * 16 + lrow * 4] = pk;
      }

    // O^T += V P^T; denominator via ones-row. V-frags loaded once, used twice.
    __builtin_amdgcn_s_setprio(1);
#pragma unroll
    for (int ks = 0; ks < 2; ks++) {
      bf16x8 pf0 = *(const bf16x8*)&Ps[wave][lcol][ks * 32 + lrow * 8];
      bf16x8 pf1 = *(const bf16x8*)&Ps[wave][16 + lcol][ks * 32 + lrow * 8];
      accS[0] = __builtin_amdgcn_mfma_f32_16x16x32_bf16(af1, pf0, accS[0], 0, 0, 0);
      accS[1] = __builtin_amdgcn_mfma_f32_16x16x32_bf16(af1, pf1, accS[1], 0, 0, 0);
#pragma unroll
      for (int mt = 0; mt < 4; mt++) {
        bf16x8 vf = *(const bf16x8*)&Vs[mt * 16 + lcol][ks * 32 + lrow * 8];
        accO[0][mt] = __builtin_amdgcn_mfma_f32_16x16x32_bf16(vf, pf0, accO[0][mt], 0, 0, 0);
        accO[1][mt] = __builtin_amdgcn_mfma_f32_16x16x32_bf16(vf, pf1, accO[1][mt], 0, 0, 0);
      }
    }
    __builtin_amdgcn_s_setprio(0);
  }

  // epilogue per q-half: l = C[0][q=lcol] of ones-row acc -> lane lcol, reg 0
#pragma unroll
  for (int qh = 0; qh < 2; qh++) {
    float lsum = __shfl(accS[qh][0], lcol);
    float linv = 1.f / lsum;
    int t = q0w + qh * 16 + lcol;
    size_t base = ((size_t)b * T_ + t) * D_ + h * HD_;
#pragma unroll
    for (int mt = 0; mt < 4; mt++) {
      uint2 pk;
      pk.x = pkbf(accO[qh][mt][0] * linv, accO[qh][mt][1] * linv);
      pk.y = pkbf(accO[qh][mt][2] * linv, accO[qh][mt][3] * linv);
      *(uint2*)&ob[base + mt * 16 + lrow * 4] = pk;
    }
  }
}

extern "C" void kernel_launch(void* const* d_in, const int* in_sizes, int n_in,
                              void* d_out, int out_size, void* d_ws, size_t ws_size,
                              hipStream_t stream) {
  (void)in_sizes; (void)n_in; (void)out_size; (void)ws_size;
  const float* x  = (const float*)d_in[0];
  const float* wq = (const float*)d_in[1];
  const float* bq = (const float*)d_in[2];
  const float* wk = (const float*)d_in[3];
  const float* bk = (const float*)d_in[4];
  const float* wv = (const float*)d_in[5];
  const float* bv = (const float*)d_in[6];
  const float* wo = (const float*)d_in[7];
  const float* bo = (const float*)d_in[8];
  float* out = (float*)d_out;

  char* ws = (char*)d_ws;
  ushort* xb     = (ushort*)(ws);              // 16 MB  x as bf16 (M x K)
  ushort* wt_qkv = (ushort*)(ws + 16777216);   // 6 MB   [wq|wk|wv]^T (3072 x 1024)
  ushort* wt_o   = (ushort*)(ws + 23068672);   // 2 MB   wo^T
  ushort* qb     = (ushort*)(ws + 25165824);   // 16 MB  Q (B,H,T,HD), pre-scaled
  ushort* kb     = (ushort*)(ws + 41943040);   // 16 MB  K (B,H,T,HD)
  ushort* vtb    = (ushort*)(ws + 58720256);   // 16 MB  V (B,H,HD,T)
  ushort* ob     = (ushort*)(ws + 75497472);   // 16 MB  attn out (B,T,D)

  cast_x_kernel<<<8192, 256, 0, stream>>>(x, xb);
  transpose_w_kernel<<<dim3(32, 32, 4), 256, 0, stream>>>(wq, wk, wv, wo, wt_qkv, wt_o);
  gemm_kernel<<<dim3(24, 64), 256, 0, stream>>>(xb, wt_qkv, 0, bq, bk, bv, qb, kb, vtb, nullptr);
  flash_kernel<<<dim3(16, 64), 256, 0, stream>>>(qb, kb, vtb, ob);
  gemm_kernel<<<dim3(8, 64), 256, 0, stream>>>(ob, wt_o, 1, bo, nullptr, nullptr,
                                               nullptr, nullptr, nullptr, out);
}

// Round 3
// 259.239 us; speedup vs baseline: 1.0432x; 1.0432x over previous
//
#include <hip/hip_runtime.h>

typedef __bf16 bf16x8 __attribute__((ext_vector_type(8)));
typedef float f32x4 __attribute__((ext_vector_type(4)));

#define B_ 4
#define T_ 2048
#define D_ 1024
#define H_ 16
#define HD_ 64
#define M_ 8192
// 1/sqrt(64) * log2(e), folded into Q so softmax uses exp2
#define QSCALE 0.1803368801111204f

__device__ __forceinline__ ushort f2b(float f) {
  union { float f; unsigned u; } v; v.f = f;
  unsigned u = v.u;
  return (ushort)((u + 0x7FFFu + ((u >> 16) & 1u)) >> 16);
}

// pack two floats to bf16 pair (round-half-up: +0x8000 then take hi16)
__device__ __forceinline__ unsigned pkbf(float a, float b) {
  union { float f; unsigned u; } va, vb; va.f = a; vb.f = b;
  return __builtin_amdgcn_perm(vb.u + 0x8000u, va.u + 0x8000u, 0x07060302u);
}

// async global->LDS, 16B per lane. LDS dest must be wave-uniform base + lane*16.
__device__ __forceinline__ void gll16(const void* g, void* l) {
  __builtin_amdgcn_global_load_lds(
      (const __attribute__((address_space(1))) unsigned*)g,
      (__attribute__((address_space(3))) unsigned*)l, 16, 0, 0);
}

__global__ __launch_bounds__(256) void cast_x_kernel(const float* __restrict__ x,
                                                     ushort* __restrict__ xb) {
  int idx = blockIdx.x * 256 + threadIdx.x;
  float4 v = ((const float4*)x)[idx];
  ushort4 o;
  o.x = f2b(v.x); o.y = f2b(v.y); o.z = f2b(v.z); o.w = f2b(v.w);
  ((ushort4*)xb)[idx] = o;
}

// 32x32 tiled transpose+cast: dst[n][k] = src[k][n], bf16 out
__global__ __launch_bounds__(256) void transpose_w_kernel(
    const float* __restrict__ wq, const float* __restrict__ wk,
    const float* __restrict__ wv, const float* __restrict__ wo,
    ushort* __restrict__ wt_qkv, ushort* __restrict__ wt_o) {
  __shared__ float tile[32][33];
  int z = blockIdx.z;
  const float* src = (z == 0) ? wq : (z == 1) ? wk : (z == 2) ? wv : wo;
  ushort* dst = (z < 3) ? (wt_qkv + (size_t)z * D_ * D_) : wt_o;
  int n0 = blockIdx.x * 32, k0 = blockIdx.y * 32;
  int tx = threadIdx.x & 31, ty = threadIdx.x >> 5;
  for (int i = 0; i < 4; i++) {
    int r = ty + i * 8;
    tile[r][tx] = src[(size_t)(k0 + r) * D_ + n0 + tx];
  }
  __syncthreads();
  for (int i = 0; i < 4; i++) {
    int r = ty + i * 8;
    dst[(size_t)(n0 + r) * D_ + k0 + tx] = f2b(tile[tx][r]);
  }
}

// C = A(MxK) * Bt(NxK)^T, 128x128 tile, BK=64, bf16 MFMA 16x16x32.
// m97 structure: double-buffered LDS filled via global_load_lds dwordx4,
// single barrier per K-step, both-sides chunk swizzle, XCD-chunked remap.
__global__ __launch_bounds__(256) void gemm_kernel(
    const ushort* __restrict__ A, const ushort* __restrict__ Bt, int mode,
    const float* __restrict__ bias_q, const float* __restrict__ bias_k,
    const float* __restrict__ bias_v,
    ushort* __restrict__ qb, ushort* __restrict__ kb, ushort* __restrict__ vtb,
    float* __restrict__ outf) {
  __shared__ ushort As[2][128][64];  // 32 KB
  __shared__ ushort Bs[2][128][64];  // 32 KB
  int tid = threadIdx.x;
  int wave = tid >> 6, lane = tid & 63, lrow = lane >> 4, lcol = lane & 15;

  // XCD-chunked remap: consecutive HW blocks round-robin XCDs; give each XCD
  // a contiguous chunk of work-space. nwg = 1536 (mode0) / 512 (mode1), %8==0.
  int gx = gridDim.x;
  int nwg = gx * gridDim.y;
  int orig = blockIdx.x + gx * blockIdx.y;
  int work = (orig & 7) * (nwg >> 3) + (orig >> 3);
  int m0 = (work / gx) * 128, n0 = (work % gx) * 128;
  int wm = (wave & 1) * 64, wn = (wave >> 1) * 64;

  int rb = tid >> 3;            // 0..31
  int dc = tid & 7;             // dest 16B chunk
  int scv = dc ^ (rb & 7);      // swizzled source chunk
  const ushort* aBase = A + (size_t)(m0 + rb) * D_ + scv * 8;
  const ushort* bBase = Bt + (size_t)(n0 + rb) * D_ + scv * 8;

  f32x4 zero = {0.f, 0.f, 0.f, 0.f};
  f32x4 acc[4][4];
  for (int i = 0; i < 4; i++)
    for (int j = 0; j < 4; j++) acc[i][j] = zero;

  int swz = lcol & 7;

  auto stage = [&](int buf, int k) {
#pragma unroll
    for (int g = 0; g < 4; g++) {
      gll16(aBase + (size_t)(32 * g) * D_ + k, &As[buf][0][0] + tid * 8 + g * 2048);
      gll16(bBase + (size_t)(32 * g) * D_ + k, &Bs[buf][0][0] + tid * 8 + g * 2048);
    }
  };

  stage(0, 0);  // prologue

  for (int k0 = 0; k0 < D_; k0 += 64) {
    int cur = (k0 >> 6) & 1, nxt = cur ^ 1;
    __syncthreads();  // drains vmcnt -> buf[cur] ready; prior reads of nxt done
    if (k0 + 64 < D_) stage(nxt, k0 + 64);  // async, in flight across compute

    for (int ks = 0; ks < 2; ks++) {
      bf16x8 af[4], bf[4];
      int ch = ((ks * 4 + lrow) ^ swz) * 8;
      for (int mt = 0; mt < 4; mt++)
        af[mt] = *(const bf16x8*)&As[cur][wm + mt * 16 + lcol][ch];
      for (int nt = 0; nt < 4; nt++)
        bf[nt] = *(const bf16x8*)&Bs[cur][wn + nt * 16 + lcol][ch];
      for (int mt = 0; mt < 4; mt++)
        for (int nt = 0; nt < 4; nt++)
          acc[mt][nt] = __builtin_amdgcn_mfma_f32_16x16x32_bf16(
              af[mt], bf[nt], acc[mt][nt], 0, 0, 0);
    }
  }

  if (mode == 0) {
    int proj = n0 >> 10;  // uniform per block (128 | 1024)
    const float* bias = (proj == 0) ? bias_q : (proj == 1) ? bias_k : bias_v;
    for (int mt = 0; mt < 4; mt++) {
      int gm0 = m0 + wm + mt * 16 + lrow * 4;  // 4 consecutive t, same b
      int b = gm0 >> 11, tp = gm0 & 2047;
      for (int nt = 0; nt < 4; nt++) {
        int gn = n0 + wn + nt * 16 + lcol;
        int inner = gn & 1023;
        int h = inner >> 6, hd = inner & 63;
        float bv = bias[inner];
        if (proj == 0) {
          size_t base = ((size_t)(b * H_ + h) * T_ + tp) * HD_ + hd;
          for (int r = 0; r < 4; r++)
            qb[base + (size_t)r * HD_] = f2b((acc[mt][nt][r] + bv) * QSCALE);
        } else if (proj == 1) {
          size_t base = ((size_t)(b * H_ + h) * T_ + tp) * HD_ + hd;
          for (int r = 0; r < 4; r++)
            kb[base + (size_t)r * HD_] = f2b(acc[mt][nt][r] + bv);
        } else {  // V stored transposed: (B,H,HD,T); 4 t's pack into ushort4
          ushort4 pk;
          pk.x = f2b(acc[mt][nt][0] + bv);
          pk.y = f2b(acc[mt][nt][1] + bv);
          pk.z = f2b(acc[mt][nt][2] + bv);
          pk.w = f2b(acc[mt][nt][3] + bv);
          *(ushort4*)&vtb[((size_t)(b * H_ + h) * HD_ + hd) * T_ + tp] = pk;
        }
      }
    }
  } else {
    for (int mt = 0; mt < 4; mt++) {
      int gm0 = m0 + wm + mt * 16 + lrow * 4;
      for (int nt = 0; nt < 4; nt++) {
        int gn = n0 + wn + nt * 16 + lcol;
        float bv = bias_q[gn];
        for (int r = 0; r < 4; r++)
          outf[(size_t)(gm0 + r) * D_ + gn] = acc[mt][nt][r] + bv;
      }
    }
  }
}

// Causal flash attention, fixed-base softmax (log2-unit scores, exp2, no max
// subtraction — validated in prior rounds). Round-3 change: CU-load-balanced
// block mapping. Round-2 post-mortem: with 1024 blocks / 256 CUs all resident
// at t=0, a CU owns bids {c, c+256, c+512, c+768}; the old qblk formula was
// invariant under +256, so each CU got 4 EQUAL-qblk blocks -> per-CU load
// ranged 8..128 tile-units (makespan 128 vs balanced 68; occupancy 12.5%).
// New mapping: phase k = (bid>>3)>>5 increments with +256, and
// qblk = (k>>1)*8 + (k&1 ? 7-m : m), m = (bid>>3)&3 -> every CU's four
// blocks carry qblk {m, 7-m, 8+m, 15-m} = constant 68 tile-units.
// Bijective over (bh, qblk); 8 bh per XCD kept (round-1 FETCH win).
__global__ __launch_bounds__(256) void flash_kernel(
    const ushort* __restrict__ qb, const ushort* __restrict__ kb,
    const ushort* __restrict__ vtb, ushort* __restrict__ ob) {
  __shared__ ushort Ks[64][80];      // [kv][hd]
  __shared__ ushort Vs[64][80];      // [hd][kv]  (global V pre-transposed)
  __shared__ ushort Ps[4][32][80];   // per-wave P^T strip: [q][kv]
  int tid = threadIdx.x;
  int wave = tid >> 6, lane = tid & 63, lrow = lane >> 4, lcol = lane & 15;

  int bid = blockIdx.x + (blockIdx.y << 4);  // grid (16,64) -> 0..1023
  int xcd = bid & 7;                         // HW round-robin XCD id
  int i = bid >> 3;                          // 0..127 per XCD
  int k = i >> 5;                            // residency phase 0..3 (+256 stride)
  int j5 = i & 31;
  int m = j5 & 3;
  int bh = xcd * 8 + (j5 >> 2);              // 8 bh per XCD -> K/V L2-resident
  int qblk = (k >> 1) * 8 + ((k & 1) ? 7 - m : m);  // per-CU sum = 68 units
  int b = bh >> 4, h = bh & 15;
  const ushort* qp = qb + (size_t)bh * T_ * HD_;
  const ushort* kh = kb + (size_t)bh * T_ * HD_;
  const ushort* vh = vtb + (size_t)bh * HD_ * T_;

  int r0 = tid >> 3, cb0 = (tid & 7) * 8;   // staging: row, col-chunk
  // prefetch KV tile j=0 into registers (named scalars; no-spill pattern)
  uint4 kr0 = *(const uint4*)&kh[(size_t)r0 * HD_ + cb0];
  uint4 kr1 = *(const uint4*)&kh[(size_t)(r0 + 32) * HD_ + cb0];
  uint4 vr0 = *(const uint4*)&vh[(size_t)r0 * T_ + cb0];
  uint4 vr1 = *(const uint4*)&vh[(size_t)(r0 + 32) * T_ + cb0];

  // constant ones-row A-fragment: A[m=0][*]=1, A[m>0][*]=0 (m = lcol)
  bf16x8 af1;
  {
    __bf16 ov = (__bf16)((lcol == 0) ? 1.0f : 0.0f);
    for (int i2 = 0; i2 < 8; i2++) af1[i2] = ov;
  }

  f32x4 zero = {0.f, 0.f, 0.f, 0.f};

  int q0w = qblk * 128 + wave * 32;  // wave's first q row (32 rows per wave)
  // Q as B-operand frags, two 16-q halves: [n=q=lcol][k=hd]
  bf16x8 qf[2][2];
#pragma unroll
  for (int qh = 0; qh < 2; qh++)
#pragma unroll
    for (int ks = 0; ks < 2; ks++)
      qf[qh][ks] = *(const bf16x8*)&qp[(size_t)(q0w + qh * 16 + lcol) * HD_ +
                                       ks * 32 + lrow * 8];

  f32x4 accO[2][4];  // O^T frags per q-half: rows=hd, cols=q=lcol
  f32x4 accS[2];     // ones-row accumulators: row 0 = per-q sum of P
#pragma unroll
  for (int qh = 0; qh < 2; qh++) {
    accS[qh] = zero;
    for (int mt = 0; mt < 4; mt++) accO[qh][mt] = zero;
  }

  int nj = qblk * 2 + 2;  // KV tiles 0 .. 2*qblk+1 (covers q0..q0+127)
  for (int j = 0; j < nj; j++) {
    __syncthreads();  // all waves done reading previous tile
    *(uint4*)&Ks[r0][cb0] = kr0;
    *(uint4*)&Ks[r0 + 32][cb0] = kr1;
    *(uint4*)&Vs[r0][cb0] = vr0;
    *(uint4*)&Vs[r0 + 32][cb0] = vr1;
    __syncthreads();

    // prefetch next tile
    if (j + 1 < nj) {
      int jn = j + 1;
      kr0 = *(const uint4*)&kh[(size_t)(jn * 64 + r0) * HD_ + cb0];
      kr1 = *(const uint4*)&kh[(size_t)(jn * 64 + r0 + 32) * HD_ + cb0];
      vr0 = *(const uint4*)&vh[(size_t)r0 * T_ + jn * 64 + cb0];
      vr1 = *(const uint4*)&vh[(size_t)(r0 + 32) * T_ + jn * 64 + cb0];
    }

    // wave-level skip: tile entirely above the causal boundary for this wave
    if (j * 64 > q0w + 31) continue;

    // S^T = K Q^T for both q-halves; K-frags loaded once, used twice
    f32x4 st[2][4];
#pragma unroll
    for (int qh = 0; qh < 2; qh++)
      for (int mt = 0; mt < 4; mt++) st[qh][mt] = zero;
    __builtin_amdgcn_s_setprio(1);
#pragma unroll
    for (int ks = 0; ks < 2; ks++)
#pragma unroll
      for (int mt = 0; mt < 4; mt++) {
        bf16x8 kf = *(const bf16x8*)&Ks[mt * 16 + lcol][ks * 32 + lrow * 8];
        st[0][mt] = __builtin_amdgcn_mfma_f32_16x16x32_bf16(kf, qf[0][ks], st[0][mt], 0, 0, 0);
        st[1][mt] = __builtin_amdgcn_mfma_f32_16x16x32_bf16(kf, qf[1][ks], st[1][mt], 0, 0, 0);
      }
    __builtin_amdgcn_s_setprio(0);

    if (j >= 2 * qblk) {  // diagonal region: causal mask (exact predicate)
#pragma unroll
      for (int qh = 0; qh < 2; qh++) {
        int q_g = q0w + qh * 16 + lcol;
#pragma unroll
        for (int mt = 0; mt < 4; mt++)
          for (int r = 0; r < 4; r++) {
            int kv_g = j * 64 + mt * 16 + lrow * 4 + r;
            if (kv_g > q_g) st[qh][mt][r] = -1e30f;
          }
      }
    }

    // fixed-base softmax numerator: P = exp2(S), no max, no rescale
#pragma unroll
    for (int qh = 0; qh < 2; qh++)
      for (int mt = 0; mt < 4; mt++)
        for (int r = 0; r < 4; r++)
          st[qh][mt][r] = __builtin_amdgcn_exp2f(st[qh][mt][r]);

    // P^T -> LDS (packed bf16 pairs; same-wave write->read)
#pragma unroll
    for (int qh = 0; qh < 2; qh++)
      for (int mt = 0; mt < 4; mt++) {
        uint2 pk;
        pk.x = pkbf(st[qh][mt][0], st[qh][mt][1]);
        pk.y = pkbf(st[qh][mt][2], st[qh][mt][3]);
        *(uint2*)&Ps[wave][qh * 16 + lcol][mt * 16 + lrow * 4] = pk;
      }

    // O^T += V P^T; denominator via ones-row. V-frags loaded once, used twice.
    __builtin_amdgcn_s_setprio(1);
#pragma unroll
    for (int ks = 0; ks < 2; ks++) {
      bf16x8 pf0 = *(const bf16x8*)&Ps[wave][lcol][ks * 32 + lrow * 8];
      bf16x8 pf1 = *(const bf16x8*)&Ps[wave][16 + lcol][ks * 32 + lrow * 8];
      accS[0] = __builtin_amdgcn_mfma_f32_16x16x32_bf16(af1, pf0, accS[0], 0, 0, 0);
      accS[1] = __builtin_amdgcn_mfma_f32_16x16x32_bf16(af1, pf1, accS[1], 0, 0, 0);
#pragma unroll
      for (int mt = 0; mt < 4; mt++) {
        bf16x8 vf = *(const bf16x8*)&Vs[mt * 16 + lcol][ks * 32 + lrow * 8];
        accO[0][mt] = __builtin_amdgcn_mfma_f32_16x16x32_bf16(vf, pf0, accO[0][mt], 0, 0, 0);
        accO[1][mt] = __builtin_amdgcn_mfma_f32_16x16x32_bf16(vf, pf1, accO[1][mt], 0, 0, 0);
      }
    }
    __builtin_amdgcn_s_setprio(0);
  }

  // epilogue per q-half: l = C[0][q=lcol] of ones-row acc -> lane lcol, reg 0
#pragma unroll
  for (int qh = 0; qh < 2; qh++) {
    float lsum = __shfl(accS[qh][0], lcol);
    float linv = 1.f / lsum;
    int t = q0w + qh * 16 + lcol;
    size_t base = ((size_t)b * T_ + t) * D_ + h * HD_;
#pragma unroll
    for (int mt = 0; mt < 4; mt++) {
      uint2 pk;
      pk.x = pkbf(accO[qh][mt][0] * linv, accO[qh][mt][1] * linv);
      pk.y = pkbf(accO[qh][mt][2] * linv, accO[qh][mt][3] * linv);
      *(uint2*)&ob[base + mt * 16 + lrow * 4] = pk;
    }
  }
}

extern "C" void kernel_launch(void* const* d_in, const int* in_sizes, int n_in,
                              void* d_out, int out_size, void* d_ws, size_t ws_size,
                              hipStream_t stream) {
  (void)in_sizes; (void)n_in; (void)out_size; (void)ws_size;
  const float* x  = (const float*)d_in[0];
  const float* wq = (const float*)d_in[1];
  const float* bq = (const float*)d_in[2];
  const float* wk = (const float*)d_in[3];
  const float* bk = (const float*)d_in[4];
  const float* wv = (const float*)d_in[5];
  const float* bv = (const float*)d_in[6];
  const float* wo = (const float*)d_in[7];
  const float* bo = (const float*)d_in[8];
  float* out = (float*)d_out;

  char* ws = (char*)d_ws;
  ushort* xb     = (ushort*)(ws);              // 16 MB  x as bf16 (M x K)
  ushort* wt_qkv = (ushort*)(ws + 16777216);   // 6 MB   [wq|wk|wv]^T (3072 x 1024)
  ushort* wt_o   = (ushort*)(ws + 23068672);   // 2 MB   wo^T
  ushort* qb     = (ushort*)(ws + 25165824);   // 16 MB  Q (B,H,T,HD), pre-scaled
  ushort* kb     = (ushort*)(ws + 41943040);   // 16 MB  K (B,H,T,HD)
  ushort* vtb    = (ushort*)(ws + 58720256);   // 16 MB  V (B,H,HD,T)
  ushort* ob     = (ushort*)(ws + 75497472);   // 16 MB  attn out (B,T,D)

  cast_x_kernel<<<8192, 256, 0, stream>>>(x, xb);
  transpose_w_kernel<<<dim3(32, 32, 4), 256, 0, stream>>>(wq, wk, wv, wo, wt_qkv, wt_o);
  gemm_kernel<<<dim3(24, 64), 256, 0, stream>>>(xb, wt_qkv, 0, bq, bk, bv, qb, kb, vtb, nullptr);
  flash_kernel<<<dim3(16, 64), 256, 0, stream>>>(qb, kb, vtb, ob);
  gemm_kernel<<<dim3(8, 64), 256, 0, stream>>>(ob, wt_o, 1, bo, nullptr, nullptr,
                                               nullptr, nullptr, nullptr, out);
}

// Round 4
// 246.969 us; speedup vs baseline: 1.0950x; 1.0497x over previous
//
#include <hip/hip_runtime.h>

typedef __bf16 bf16x8 __attribute__((ext_vector_type(8)));
typedef float f32x4 __attribute__((ext_vector_type(4)));

#define B_ 4
#define T_ 2048
#define D_ 1024
#define H_ 16
#define HD_ 64
#define M_ 8192
// 1/sqrt(64) * log2(e), folded into Q so softmax uses exp2
#define QSCALE 0.1803368801111204f

__device__ __forceinline__ ushort f2b(float f) {
  union { float f; unsigned u; } v; v.f = f;
  unsigned u = v.u;
  return (ushort)((u + 0x7FFFu + ((u >> 16) & 1u)) >> 16);
}

// pack two floats to bf16 pair (round-half-up: +0x8000 then take hi16)
__device__ __forceinline__ unsigned pkbf(float a, float b) {
  union { float f; unsigned u; } va, vb; va.f = a; vb.f = b;
  return __builtin_amdgcn_perm(vb.u + 0x8000u, va.u + 0x8000u, 0x07060302u);
}

// async global->LDS, 16B per lane. LDS dest must be wave-uniform base + lane*16.
__device__ __forceinline__ void gll16(const void* g, void* l) {
  __builtin_amdgcn_global_load_lds(
      (const __attribute__((address_space(1))) unsigned*)g,
      (__attribute__((address_space(3))) unsigned*)l, 16, 0, 0);
}

__global__ __launch_bounds__(256) void cast_x_kernel(const float* __restrict__ x,
                                                     ushort* __restrict__ xb) {
  int idx = blockIdx.x * 256 + threadIdx.x;
  float4 v = ((const float4*)x)[idx];
  ushort4 o;
  o.x = f2b(v.x); o.y = f2b(v.y); o.z = f2b(v.z); o.w = f2b(v.w);
  ((ushort4*)xb)[idx] = o;
}

// 32x32 tiled transpose+cast: dst[n][k] = src[k][n], bf16 out
__global__ __launch_bounds__(256) void transpose_w_kernel(
    const float* __restrict__ wq, const float* __restrict__ wk,
    const float* __restrict__ wv, const float* __restrict__ wo,
    ushort* __restrict__ wt_qkv, ushort* __restrict__ wt_o) {
  __shared__ float tile[32][33];
  int z = blockIdx.z;
  const float* src = (z == 0) ? wq : (z == 1) ? wk : (z == 2) ? wv : wo;
  ushort* dst = (z < 3) ? (wt_qkv + (size_t)z * D_ * D_) : wt_o;
  int n0 = blockIdx.x * 32, k0 = blockIdx.y * 32;
  int tx = threadIdx.x & 31, ty = threadIdx.x >> 5;
  for (int i = 0; i < 4; i++) {
    int r = ty + i * 8;
    tile[r][tx] = src[(size_t)(k0 + r) * D_ + n0 + tx];
  }
  __syncthreads();
  for (int i = 0; i < 4; i++) {
    int r = ty + i * 8;
    dst[(size_t)(n0 + r) * D_ + k0 + tx] = f2b(tile[tx][r]);
  }
}

// C = A(MxK) * Bt(NxK)^T, 128x128 tile, BK=64, bf16 MFMA 16x16x32.
// m97 structure: double-buffered LDS filled via global_load_lds dwordx4,
// single barrier per K-step, both-sides chunk swizzle, XCD-chunked remap.
// (unchanged from round 3)
__global__ __launch_bounds__(256) void gemm_kernel(
    const ushort* __restrict__ A, const ushort* __restrict__ Bt, int mode,
    const float* __restrict__ bias_q, const float* __restrict__ bias_k,
    const float* __restrict__ bias_v,
    ushort* __restrict__ qb, ushort* __restrict__ kb, ushort* __restrict__ vtb,
    float* __restrict__ outf) {
  __shared__ ushort As[2][128][64];  // 32 KB
  __shared__ ushort Bs[2][128][64];  // 32 KB
  int tid = threadIdx.x;
  int wave = tid >> 6, lane = tid & 63, lrow = lane >> 4, lcol = lane & 15;

  int gx = gridDim.x;
  int nwg = gx * gridDim.y;
  int orig = blockIdx.x + gx * blockIdx.y;
  int work = (orig & 7) * (nwg >> 3) + (orig >> 3);
  int m0 = (work / gx) * 128, n0 = (work % gx) * 128;
  int wm = (wave & 1) * 64, wn = (wave >> 1) * 64;

  int rb = tid >> 3;            // 0..31
  int dc = tid & 7;             // dest 16B chunk
  int scv = dc ^ (rb & 7);      // swizzled source chunk
  const ushort* aBase = A + (size_t)(m0 + rb) * D_ + scv * 8;
  const ushort* bBase = Bt + (size_t)(n0 + rb) * D_ + scv * 8;

  f32x4 zero = {0.f, 0.f, 0.f, 0.f};
  f32x4 acc[4][4];
  for (int i = 0; i < 4; i++)
    for (int j = 0; j < 4; j++) acc[i][j] = zero;

  int swz = lcol & 7;

  auto stage = [&](int buf, int k) {
#pragma unroll
    for (int g = 0; g < 4; g++) {
      gll16(aBase + (size_t)(32 * g) * D_ + k, &As[buf][0][0] + tid * 8 + g * 2048);
      gll16(bBase + (size_t)(32 * g) * D_ + k, &Bs[buf][0][0] + tid * 8 + g * 2048);
    }
  };

  stage(0, 0);  // prologue

  for (int k0 = 0; k0 < D_; k0 += 64) {
    int cur = (k0 >> 6) & 1, nxt = cur ^ 1;
    __syncthreads();  // drains vmcnt -> buf[cur] ready; prior reads of nxt done
    if (k0 + 64 < D_) stage(nxt, k0 + 64);  // async, in flight across compute

    for (int ks = 0; ks < 2; ks++) {
      bf16x8 af[4], bf[4];
      int ch = ((ks * 4 + lrow) ^ swz) * 8;
      for (int mt = 0; mt < 4; mt++)
        af[mt] = *(const bf16x8*)&As[cur][wm + mt * 16 + lcol][ch];
      for (int nt = 0; nt < 4; nt++)
        bf[nt] = *(const bf16x8*)&Bs[cur][wn + nt * 16 + lcol][ch];
      for (int mt = 0; mt < 4; mt++)
        for (int nt = 0; nt < 4; nt++)
          acc[mt][nt] = __builtin_amdgcn_mfma_f32_16x16x32_bf16(
              af[mt], bf[nt], acc[mt][nt], 0, 0, 0);
    }
  }

  if (mode == 0) {
    int proj = n0 >> 10;  // uniform per block (128 | 1024)
    const float* bias = (proj == 0) ? bias_q : (proj == 1) ? bias_k : bias_v;
    for (int mt = 0; mt < 4; mt++) {
      int gm0 = m0 + wm + mt * 16 + lrow * 4;  // 4 consecutive t, same b
      int b = gm0 >> 11, tp = gm0 & 2047;
      for (int nt = 0; nt < 4; nt++) {
        int gn = n0 + wn + nt * 16 + lcol;
        int inner = gn & 1023;
        int h = inner >> 6, hd = inner & 63;
        float bv = bias[inner];
        if (proj == 0) {
          size_t base = ((size_t)(b * H_ + h) * T_ + tp) * HD_ + hd;
          for (int r = 0; r < 4; r++)
            qb[base + (size_t)r * HD_] = f2b((acc[mt][nt][r] + bv) * QSCALE);
        } else if (proj == 1) {
          size_t base = ((size_t)(b * H_ + h) * T_ + tp) * HD_ + hd;
          for (int r = 0; r < 4; r++)
            kb[base + (size_t)r * HD_] = f2b(acc[mt][nt][r] + bv);
        } else {  // V stored transposed: (B,H,HD,T); 4 t's pack into ushort4
          ushort4 pk;
          pk.x = f2b(acc[mt][nt][0] + bv);
          pk.y = f2b(acc[mt][nt][1] + bv);
          pk.z = f2b(acc[mt][nt][2] + bv);
          pk.w = f2b(acc[mt][nt][3] + bv);
          *(ushort4*)&vtb[((size_t)(b * H_ + h) * HD_ + hd) * T_ + tp] = pk;
        }
      }
    }
  } else {
    for (int mt = 0; mt < 4; mt++) {
      int gm0 = m0 + wm + mt * 16 + lrow * 4;
      for (int nt = 0; nt < 4; nt++) {
        int gn = n0 + wn + nt * 16 + lcol;
        float bv = bias_q[gn];
        for (int r = 0; r < 4; r++)
          outf[(size_t)(gm0 + r) * D_ + gn] = acc[mt][nt][r] + bv;
      }
    }
  }
}

// Causal flash attention, fixed-base softmax (log2-unit scores, exp2, no max
// subtraction — validated). Round-4 structure:
//  - Balanced pairing: each block runs q-blocks (15-p, p) sequentially ->
//    every block is exactly 34 KV-tile iterations. Grid (8,64)=512, 2
//    blocks/CU, uniform makespan (round-3 post-mortem: unequal block lengths
//    left CUs ~2-block-resident on average; this makes residency flat).
//  - Stride-64 XOR-swizzled LDS (chunk ^= row&7, the GEMM/m201 scheme) for
//    K, V, and P: per-phase bank spread is uniform for every access pattern
//    (staging writes, b128 frag reads, b64 P writes). Kills the constant
//    6.49M conflict cycles that tracked the P-path at stride 160B.
//  - Double-buffered K/V with ONE barrier per tile: iter g = [compute
//    buf[g&1]] [write buf[(g+1)&1] from prefetch regs] [issue loads g+2]
//    [sync]. Reads of buf[(g+1)&1] finished before the PREVIOUS barrier;
//    writes are published by THIS barrier.
__global__ __launch_bounds__(256) void flash_kernel(
    const ushort* __restrict__ qb, const ushort* __restrict__ kb,
    const ushort* __restrict__ vtb, ushort* __restrict__ ob) {
  __shared__ ushort Ks2[2][64][64];  // 16 KB  [buf][kv][hd] (swizzled chunks)
  __shared__ ushort Vs2[2][64][64];  // 16 KB  [buf][hd][kv] (swizzled chunks)
  __shared__ ushort Ps[4][32][64];   // 16 KB  per-wave P^T strip (swizzled)
  int tid = threadIdx.x;
  int wave = tid >> 6, lane = tid & 63, lrow = lane >> 4, lcol = lane & 15;

  int bid = blockIdx.x + (blockIdx.y << 3);  // grid (8,64) -> 0..511
  int xcd = bid & 7;                         // HW round-robin XCD id
  int slot = bid >> 3;                       // 0..63 per XCD
  int bh = xcd * 8 + (slot >> 3);            // 8 bh per XCD -> K/V L2-resident
  int p = slot & 7;
  int qb0 = 15 - p, qb1 = p;                 // heavy then light: 34 tiles total
  int b = bh >> 4, h = bh & 15;
  const ushort* qp = qb + (size_t)bh * T_ * HD_;
  const ushort* kh = kb + (size_t)bh * T_ * HD_;
  const ushort* vh = vtb + (size_t)bh * HD_ * T_;

  int n0 = 2 * qb0 + 2;
  int ntot = n0 + 2 * qb1 + 2;  // 34

  int r0 = tid >> 3, dc = tid & 7;          // staging: row, 16B chunk
  int wsl = (dc ^ (r0 & 7)) * 8;            // swizzled slot (ushort offset)
  int rsw = lcol & 7;                       // read-side swizzle key

  uint4 kr0, kr1, vr0, vr1;                 // prefetch regs (one KV tile)
  auto gload = [&](int jt) {
    kr0 = *(const uint4*)&kh[(size_t)(jt * 64 + r0) * HD_ + dc * 8];
    kr1 = *(const uint4*)&kh[(size_t)(jt * 64 + r0 + 32) * HD_ + dc * 8];
    vr0 = *(const uint4*)&vh[(size_t)r0 * T_ + jt * 64 + dc * 8];
    vr1 = *(const uint4*)&vh[(size_t)(r0 + 32) * T_ + jt * 64 + dc * 8];
  };
  auto swrite = [&](int buf) {
    *(uint4*)&Ks2[buf][r0][wsl] = kr0;
    *(uint4*)&Ks2[buf][r0 + 32][wsl] = kr1;   // (r0+32)&7 == r0&7
    *(uint4*)&Vs2[buf][r0][wsl] = vr0;
    *(uint4*)&Vs2[buf][r0 + 32][wsl] = vr1;
  };

  // constant ones-row A-fragment: A[m=0][*]=1, A[m>0][*]=0 (m = lcol)
  bf16x8 af1;
  {
    __bf16 ov = (__bf16)((lcol == 0) ? 1.0f : 0.0f);
    for (int i2 = 0; i2 < 8; i2++) af1[i2] = ov;
  }

  f32x4 zero = {0.f, 0.f, 0.f, 0.f};

  // prologue: tile seq0 -> buf0; prefetch seq1
  gload(0);
  swrite(0);
  gload(1);
  __syncthreads();

  // both passes' Q fragments up front (hides pass-1 Q latency)
  int q0wA = qb0 * 128 + wave * 32, q0wB = qb1 * 128 + wave * 32;
  bf16x8 qfA[2][2], qfB[2][2];
#pragma unroll
  for (int qh = 0; qh < 2; qh++)
#pragma unroll
    for (int ks = 0; ks < 2; ks++) {
      qfA[qh][ks] = *(const bf16x8*)&qp[(size_t)(q0wA + qh * 16 + lcol) * HD_ +
                                        ks * 32 + lrow * 8];
      qfB[qh][ks] = *(const bf16x8*)&qp[(size_t)(q0wB + qh * 16 + lcol) * HD_ +
                                        ks * 32 + lrow * 8];
    }

  auto run_pass = [&](int qblk, int q0w, int base, const bf16x8 qf[2][2]) {
    f32x4 accO[2][4];  // O^T frags per q-half: rows=hd, cols=q=lcol
    f32x4 accS[2];     // ones-row accumulators: row 0 = per-q sum of P
#pragma unroll
    for (int qh = 0; qh < 2; qh++) {
      accS[qh] = zero;
      for (int mt = 0; mt < 4; mt++) accO[qh][mt] = zero;
    }

    int nj = 2 * qblk + 2;
    for (int j = 0; j < nj; j++) {
      int g = base + j, cur = g & 1;
      bool active = (j * 64 <= q0w + 31);

      if (active) {
        // S^T = K Q^T for both q-halves; K-frags loaded once, used twice
        f32x4 st[2][4];
#pragma unroll
        for (int qh = 0; qh < 2; qh++)
          for (int mt = 0; mt < 4; mt++) st[qh][mt] = zero;
        __builtin_amdgcn_s_setprio(1);
#pragma unroll
        for (int ks = 0; ks < 2; ks++)
#pragma unroll
          for (int mt = 0; mt < 4; mt++) {
            bf16x8 kf = *(const bf16x8*)&Ks2[cur][mt * 16 + lcol]
                                            [((ks * 4 + lrow) ^ rsw) * 8];
            st[0][mt] = __builtin_amdgcn_mfma_f32_16x16x32_bf16(kf, qf[0][ks], st[0][mt], 0, 0, 0);
            st[1][mt] = __builtin_amdgcn_mfma_f32_16x16x32_bf16(kf, qf[1][ks], st[1][mt], 0, 0, 0);
          }
        __builtin_amdgcn_s_setprio(0);

        if (j >= 2 * qblk) {  // diagonal region: causal mask
#pragma unroll
          for (int qh = 0; qh < 2; qh++) {
            int q_g = q0w + qh * 16 + lcol;
#pragma unroll
            for (int mt = 0; mt < 4; mt++)
              for (int r = 0; r < 4; r++) {
                int kv_g = j * 64 + mt * 16 + lrow * 4 + r;
                if (kv_g > q_g) st[qh][mt][r] = -1e30f;
              }
          }
        }

        // fixed-base softmax numerator: P = exp2(S), no max, no rescale
#pragma unroll
        for (int qh = 0; qh < 2; qh++)
          for (int mt = 0; mt < 4; mt++)
            for (int r = 0; r < 4; r++)
              st[qh][mt][r] = __builtin_amdgcn_exp2f(st[qh][mt][r]);

        // P^T -> LDS (packed bf16 pairs; same-wave write->read; swizzled)
#pragma unroll
        for (int qh = 0; qh < 2; qh++)
          for (int mt = 0; mt < 4; mt++) {
            uint2 pk;
            pk.x = pkbf(st[qh][mt][0], st[qh][mt][1]);
            pk.y = pkbf(st[qh][mt][2], st[qh][mt][3]);
            int sl = ((2 * mt + (lrow >> 1)) ^ rsw) * 8 + (lrow & 1) * 4;
            *(uint2*)&Ps[wave][qh * 16 + lcol][sl] = pk;
          }

        // O^T += V P^T; denominator via ones-row. V-frags used twice.
        __builtin_amdgcn_s_setprio(1);
#pragma unroll
        for (int ks = 0; ks < 2; ks++) {
          int ch = ((ks * 4 + lrow) ^ rsw) * 8;
          bf16x8 pf0 = *(const bf16x8*)&Ps[wave][lcol][ch];
          bf16x8 pf1 = *(const bf16x8*)&Ps[wave][16 + lcol][ch];
          accS[0] = __builtin_amdgcn_mfma_f32_16x16x32_bf16(af1, pf0, accS[0], 0, 0, 0);
          accS[1] = __builtin_amdgcn_mfma_f32_16x16x32_bf16(af1, pf1, accS[1], 0, 0, 0);
#pragma unroll
          for (int mt = 0; mt < 4; mt++) {
            bf16x8 vf = *(const bf16x8*)&Vs2[cur][mt * 16 + lcol][ch];
            accO[0][mt] = __builtin_amdgcn_mfma_f32_16x16x32_bf16(vf, pf0, accO[0][mt], 0, 0, 0);
            accO[1][mt] = __builtin_amdgcn_mfma_f32_16x16x32_bf16(vf, pf1, accO[1][mt], 0, 0, 0);
          }
        }
        __builtin_amdgcn_s_setprio(0);
      }

      // stage next tile (regs hold seq g+1) into the other buffer; its old
      // readers finished before the PREVIOUS barrier.
      if (g + 1 < ntot) swrite(cur ^ 1);
      // issue loads for seq g+2
      if (g + 2 < ntot) {
        int s = g + 2;
        gload(s < n0 ? s : s - n0);
      }
      __syncthreads();  // publish writes for next iteration
    }

    // epilogue: l = C[0][q=lcol] of ones-row acc -> lane lcol, reg 0
#pragma unroll
    for (int qh = 0; qh < 2; qh++) {
      float lsum = __shfl(accS[qh][0], lcol);
      float linv = 1.f / lsum;
      int t = q0w + qh * 16 + lcol;
      size_t base2 = ((size_t)b * T_ + t) * D_ + h * HD_;
#pragma unroll
      for (int mt = 0; mt < 4; mt++) {
        uint2 pk;
        pk.x = pkbf(accO[qh][mt][0] * linv, accO[qh][mt][1] * linv);
        pk.y = pkbf(accO[qh][mt][2] * linv, accO[qh][mt][3] * linv);
        *(uint2*)&ob[base2 + mt * 16 + lrow * 4] = pk;
      }
    }
  };

  run_pass(qb0, q0wA, 0, qfA);
  run_pass(qb1, q0wB, n0, qfB);
}

extern "C" void kernel_launch(void* const* d_in, const int* in_sizes, int n_in,
                              void* d_out, int out_size, void* d_ws, size_t ws_size,
                              hipStream_t stream) {
  (void)in_sizes; (void)n_in; (void)out_size; (void)ws_size;
  const float* x  = (const float*)d_in[0];
  const float* wq = (const float*)d_in[1];
  const float* bq = (const float*)d_in[2];
  const float* wk = (const float*)d_in[3];
  const float* bk = (const float*)d_in[4];
  const float* wv = (const float*)d_in[5];
  const float* bv = (const float*)d_in[6];
  const float* wo = (const float*)d_in[7];
  const float* bo = (const float*)d_in[8];
  float* out = (float*)d_out;

  char* ws = (char*)d_ws;
  ushort* xb     = (ushort*)(ws);              // 16 MB  x as bf16 (M x K)
  ushort* wt_qkv = (ushort*)(ws + 16777216);   // 6 MB   [wq|wk|wv]^T (3072 x 1024)
  ushort* wt_o   = (ushort*)(ws + 23068672);   // 2 MB   wo^T
  ushort* qb     = (ushort*)(ws + 25165824);   // 16 MB  Q (B,H,T,HD), pre-scaled
  ushort* kb     = (ushort*)(ws + 41943040);   // 16 MB  K (B,H,T,HD)
  ushort* vtb    = (ushort*)(ws + 58720256);   // 16 MB  V (B,H,HD,T)
  ushort* ob     = (ushort*)(ws + 75497472);   // 16 MB  attn out (B,T,D)

  cast_x_kernel<<<8192, 256, 0, stream>>>(x, xb);
  transpose_w_kernel<<<dim3(32, 32, 4), 256, 0, stream>>>(wq, wk, wv, wo, wt_qkv, wt_o);
  gemm_kernel<<<dim3(24, 64), 256, 0, stream>>>(xb, wt_qkv, 0, bq, bk, bv, qb, kb, vtb, nullptr);
  flash_kernel<<<dim3(8, 64), 256, 0, stream>>>(qb, kb, vtb, ob);
  gemm_kernel<<<dim3(8, 64), 256, 0, stream>>>(ob, wt_o, 1, bo, nullptr, nullptr,
                                               nullptr, nullptr, nullptr, out);
}

// Round 5
// 246.848 us; speedup vs baseline: 1.0956x; 1.0005x over previous
//
#include <hip/hip_runtime.h>

typedef __bf16 bf16x8 __attribute__((ext_vector_type(8)));
typedef float f32x4 __attribute__((ext_vector_type(4)));

#define B_ 4
#define T_ 2048
#define D_ 1024
#define H_ 16
#define HD_ 64
#define M_ 8192
// 1/sqrt(64) * log2(e), folded into Q so softmax uses exp2
#define QSCALE 0.1803368801111204f

__device__ __forceinline__ ushort f2b(float f) {
  union { float f; unsigned u; } v; v.f = f;
  unsigned u = v.u;
  return (ushort)((u + 0x7FFFu + ((u >> 16) & 1u)) >> 16);
}

// pack two floats to bf16 pair (round-half-up: +0x8000 then take hi16)
__device__ __forceinline__ unsigned pkbf(float a, float b) {
  union { float f; unsigned u; } va, vb; va.f = a; vb.f = b;
  return __builtin_amdgcn_perm(vb.u + 0x8000u, va.u + 0x8000u, 0x07060302u);
}

// async global->LDS, 16B per lane. LDS dest must be wave-uniform base + lane*16.
__device__ __forceinline__ void gll16(const void* g, void* l) {
  __builtin_amdgcn_global_load_lds(
      (const __attribute__((address_space(1))) unsigned*)g,
      (__attribute__((address_space(3))) unsigned*)l, 16, 0, 0);
}

__global__ __launch_bounds__(256) void cast_x_kernel(const float* __restrict__ x,
                                                     ushort* __restrict__ xb) {
  int idx = blockIdx.x * 256 + threadIdx.x;
  float4 v = ((const float4*)x)[idx];
  ushort4 o;
  o.x = f2b(v.x); o.y = f2b(v.y); o.z = f2b(v.z); o.w = f2b(v.w);
  ((ushort4*)xb)[idx] = o;
}

// 32x32 tiled transpose+cast: dst[n][k] = src[k][n], bf16 out
__global__ __launch_bounds__(256) void transpose_w_kernel(
    const float* __restrict__ wq, const float* __restrict__ wk,
    const float* __restrict__ wv, const float* __restrict__ wo,
    ushort* __restrict__ wt_qkv, ushort* __restrict__ wt_o) {
  __shared__ float tile[32][33];
  int z = blockIdx.z;
  const float* src = (z == 0) ? wq : (z == 1) ? wk : (z == 2) ? wv : wo;
  ushort* dst = (z < 3) ? (wt_qkv + (size_t)z * D_ * D_) : wt_o;
  int n0 = blockIdx.x * 32, k0 = blockIdx.y * 32;
  int tx = threadIdx.x & 31, ty = threadIdx.x >> 5;
  for (int i = 0; i < 4; i++) {
    int r = ty + i * 8;
    tile[r][tx] = src[(size_t)(k0 + r) * D_ + n0 + tx];
  }
  __syncthreads();
  for (int i = 0; i < 4; i++) {
    int r = ty + i * 8;
    dst[(size_t)(n0 + r) * D_ + k0 + tx] = f2b(tile[tx][r]);
  }
}

// C = A(MxK) * Bt(NxK)^T, 128x128 tile, BK=64, bf16 MFMA 16x16x32.
// m97 structure: double-buffered LDS via global_load_lds dwordx4, single
// barrier per K-step, both-sides chunk swizzle, XCD-chunked remap.
// Round-5: Q/K epilogue uses a 4-lane in-register 4x4 transpose so each lane
// stores ushort4 (8B) of 4 consecutive hd instead of 64 scattered 2B stores.
// f2b rounding kept bit-exact with prior rounds.
__global__ __launch_bounds__(256) void gemm_kernel(
    const ushort* __restrict__ A, const ushort* __restrict__ Bt, int mode,
    const float* __restrict__ bias_q, const float* __restrict__ bias_k,
    const float* __restrict__ bias_v,
    ushort* __restrict__ qb, ushort* __restrict__ kb, ushort* __restrict__ vtb,
    float* __restrict__ outf) {
  __shared__ ushort As[2][128][64];  // 32 KB
  __shared__ ushort Bs[2][128][64];  // 32 KB
  int tid = threadIdx.x;
  int wave = tid >> 6, lane = tid & 63, lrow = lane >> 4, lcol = lane & 15;

  int gx = gridDim.x;
  int nwg = gx * gridDim.y;
  int orig = blockIdx.x + gx * blockIdx.y;
  int work = (orig & 7) * (nwg >> 3) + (orig >> 3);
  int m0 = (work / gx) * 128, n0 = (work % gx) * 128;
  int wm = (wave & 1) * 64, wn = (wave >> 1) * 64;

  int rb = tid >> 3;            // 0..31
  int dc = tid & 7;             // dest 16B chunk
  int scv = dc ^ (rb & 7);      // swizzled source chunk
  const ushort* aBase = A + (size_t)(m0 + rb) * D_ + scv * 8;
  const ushort* bBase = Bt + (size_t)(n0 + rb) * D_ + scv * 8;

  f32x4 zero = {0.f, 0.f, 0.f, 0.f};
  f32x4 acc[4][4];
  for (int i = 0; i < 4; i++)
    for (int j = 0; j < 4; j++) acc[i][j] = zero;

  int swz = lcol & 7;

  auto stage = [&](int buf, int k) {
#pragma unroll
    for (int g = 0; g < 4; g++) {
      gll16(aBase + (size_t)(32 * g) * D_ + k, &As[buf][0][0] + tid * 8 + g * 2048);
      gll16(bBase + (size_t)(32 * g) * D_ + k, &Bs[buf][0][0] + tid * 8 + g * 2048);
    }
  };

  stage(0, 0);  // prologue

  for (int k0 = 0; k0 < D_; k0 += 64) {
    int cur = (k0 >> 6) & 1, nxt = cur ^ 1;
    __syncthreads();  // drains vmcnt -> buf[cur] ready; prior reads of nxt done
    if (k0 + 64 < D_) stage(nxt, k0 + 64);  // async, in flight across compute

    for (int ks = 0; ks < 2; ks++) {
      bf16x8 af[4], bf[4];
      int ch = ((ks * 4 + lrow) ^ swz) * 8;
      for (int mt = 0; mt < 4; mt++)
        af[mt] = *(const bf16x8*)&As[cur][wm + mt * 16 + lcol][ch];
      for (int nt = 0; nt < 4; nt++)
        bf[nt] = *(const bf16x8*)&Bs[cur][wn + nt * 16 + lcol][ch];
      for (int mt = 0; mt < 4; mt++)
        for (int nt = 0; nt < 4; nt++)
          acc[mt][nt] = __builtin_amdgcn_mfma_f32_16x16x32_bf16(
              af[mt], bf[nt], acc[mt][nt], 0, 0, 0);
    }
  }

  if (mode == 0) {
    int proj = n0 >> 10;  // uniform per block (128 | 1024)
    const float* bias = (proj == 0) ? bias_q : (proj == 1) ? bias_k : bias_v;
    if (proj < 2) {
      // Q/K: (B,H,T,HD) layout. 4-lane transpose: lane j of each 4-lane group
      // ends with r=j's values for 4 consecutive hd -> one 8B store.
      ushort* dst = (proj == 0) ? qb : kb;
      bool isq = (proj == 0);
      int c0 = lcol & 1, c1 = lcol & 2;
      for (int mt = 0; mt < 4; mt++) {
        int gm0 = m0 + wm + mt * 16 + lrow * 4;
        int t = gm0 + (lcol & 3);
        int b = t >> 11, tp = t & 2047;
        for (int nt = 0; nt < 4; nt++) {
          int gn = n0 + wn + nt * 16 + lcol;
          int inner = gn & 1023;
          float bv = bias[inner];
          float v0 = acc[mt][nt][0] + bv, v1 = acc[mt][nt][1] + bv;
          float v2 = acc[mt][nt][2] + bv, v3 = acc[mt][nt][3] + bv;
          if (isq) { v0 *= QSCALE; v1 *= QSCALE; v2 *= QSCALE; v3 *= QSCALE; }
          // bit-exact f2b (RNE), then pack
          unsigned p0 = ((unsigned)f2b(v1) << 16) | f2b(v0);
          unsigned p1 = ((unsigned)f2b(v3) << 16) | f2b(v2);
          unsigned x0 = __shfl_xor(p0, 1), x1 = __shfl_xor(p1, 1);
          // stage 1: gather r_{c0} / r_{2+c0} pairs over the hd pair
          unsigned a0 = c0 ? __builtin_amdgcn_perm(p0, x0, 0x07060302u)
                           : __builtin_amdgcn_perm(x0, p0, 0x05040100u);
          unsigned a1 = c0 ? __builtin_amdgcn_perm(p1, x1, 0x07060302u)
                           : __builtin_amdgcn_perm(x1, p1, 0x05040100u);
          unsigned y0 = __shfl_xor(a0, 2), y1 = __shfl_xor(a1, 2);
          uint2 q2;
          q2.x = c1 ? y1 : a0;   // hd0,hd1 @ r=lcol&3
          q2.y = c1 ? a1 : y0;   // hd2,hd3 @ r=lcol&3
          int innerb = (n0 + wn + nt * 16 + (lcol & ~3)) & 1023;
          int h = innerb >> 6, hd0 = innerb & 63;
          *(uint2*)&dst[((size_t)(b * H_ + h) * T_ + tp) * HD_ + hd0] = q2;
        }
      }
    } else {  // V stored transposed: (B,H,HD,T); 4 t's pack into ushort4
      for (int mt = 0; mt < 4; mt++) {
        int gm0 = m0 + wm + mt * 16 + lrow * 4;
        int b = gm0 >> 11, tp = gm0 & 2047;
        for (int nt = 0; nt < 4; nt++) {
          int gn = n0 + wn + nt * 16 + lcol;
          int inner = gn & 1023;
          int h = inner >> 6, hd = inner & 63;
          float bv = bias[inner];
          ushort4 pk;
          pk.x = f2b(acc[mt][nt][0] + bv);
          pk.y = f2b(acc[mt][nt][1] + bv);
          pk.z = f2b(acc[mt][nt][2] + bv);
          pk.w = f2b(acc[mt][nt][3] + bv);
          *(ushort4*)&vtb[((size_t)(b * H_ + h) * HD_ + hd) * T_ + tp] = pk;
        }
      }
    }
  } else {
    for (int mt = 0; mt < 4; mt++) {
      int gm0 = m0 + wm + mt * 16 + lrow * 4;
      for (int nt = 0; nt < 4; nt++) {
        int gn = n0 + wn + nt * 16 + lcol;
        float bv = bias_q[gn];
        for (int r = 0; r < 4; r++)
          outf[(size_t)(gm0 + r) * D_ + gn] = acc[mt][nt][r] + bv;
      }
    }
  }
}

// Causal flash attention, fixed-base softmax (log2-unit scores, exp2, no max
// subtraction — validated). Round-5 structure: MERGED pair loop.
// Key insight: for the pair (qbA=15-p, qbB=p), block B's KV tiles are a strict
// prefix of A's. One loop over tiles 0..2*qbA+1 computes BOTH q-blocks against
// the same staged tile: tile-iterations per block 34 -> 32-2p, and pass-B's
// re-staging/barriers vanish. Phase-complementary CU pairing (slot s and s+32
// carry p and 7-p) keeps per-CU load constant at 50 tile-units (was 68).
// Accumulation order per q-block unchanged -> bit-exact with round 4.
#define QCOMP(qblk_, q0w_, qfv, accOv, accSv)                                   \
  do {                                                                          \
    f32x4 st[2][4];                                                             \
    for (int qh = 0; qh < 2; qh++)                                              \
      for (int mt = 0; mt < 4; mt++) st[qh][mt] = zero;                         \
    __builtin_amdgcn_s_setprio(1);                                              \
    _Pragma("unroll")                                                           \
    for (int ks = 0; ks < 2; ks++)                                              \
      _Pragma("unroll")                                                         \
      for (int mt = 0; mt < 4; mt++) {                                          \
        bf16x8 kf = *(const bf16x8*)&Ks2[cur][mt * 16 + lcol]                   \
                                        [((ks * 4 + lrow) ^ rsw) * 8];          \
        st[0][mt] = __builtin_amdgcn_mfma_f32_16x16x32_bf16(kf, qfv[0][ks],     \
                                                            st[0][mt], 0, 0, 0);\
        st[1][mt] = __builtin_amdgcn_mfma_f32_16x16x32_bf16(kf, qfv[1][ks],     \
                                                            st[1][mt], 0, 0, 0);\
      }                                                                         \
    __builtin_amdgcn_s_setprio(0);                                              \
    if (j >= 2 * (qblk_)) {                                                     \
      _Pragma("unroll")                                                         \
      for (int qh = 0; qh < 2; qh++) {                                          \
        int q_g = (q0w_) + qh * 16 + lcol;                                      \
        _Pragma("unroll")                                                       \
        for (int mt = 0; mt < 4; mt++)                                          \
          for (int r = 0; r < 4; r++) {                                         \
            int kv_g = j * 64 + mt * 16 + lrow * 4 + r;                         \
            if (kv_g > q_g) st[qh][mt][r] = -1e30f;                             \
          }                                                                     \
      }                                                                         \
    }                                                                           \
    _Pragma("unroll")                                                           \
    for (int qh = 0; qh < 2; qh++)                                              \
      for (int mt = 0; mt < 4; mt++)                                            \
        for (int r = 0; r < 4; r++)                                             \
          st[qh][mt][r] = __builtin_amdgcn_exp2f(st[qh][mt][r]);                \
    _Pragma("unroll")                                                           \
    for (int qh = 0; qh < 2; qh++)                                              \
      for (int mt = 0; mt < 4; mt++) {                                          \
        uint2 pk;                                                               \
        pk.x = pkbf(st[qh][mt][0], st[qh][mt][1]);                              \
        pk.y = pkbf(st[qh][mt][2], st[qh][mt][3]);                              \
        int sl = ((2 * mt + (lrow >> 1)) ^ rsw) * 8 + (lrow & 1) * 4;           \
        *(uint2*)&Ps[wave][qh * 16 + lcol][sl] = pk;                            \
      }                                                                         \
    __builtin_amdgcn_s_setprio(1);                                              \
    _Pragma("unroll")                                                           \
    for (int ks = 0; ks < 2; ks++) {                                            \
      int ch = ((ks * 4 + lrow) ^ rsw) * 8;                                     \
      bf16x8 pf0 = *(const bf16x8*)&Ps[wave][lcol][ch];                         \
      bf16x8 pf1 = *(const bf16x8*)&Ps[wave][16 + lcol][ch];                    \
      accSv[0] = __builtin_amdgcn_mfma_f32_16x16x32_bf16(af1, pf0, accSv[0],    \
                                                         0, 0, 0);              \
      accSv[1] = __builtin_amdgcn_mfma_f32_16x16x32_bf16(af1, pf1, accSv[1],    \
                                                         0, 0, 0);              \
      _Pragma("unroll")                                                         \
      for (int mt = 0; mt < 4; mt++) {                                          \
        bf16x8 vf = *(const bf16x8*)&Vs2[cur][mt * 16 + lcol][ch];              \
        accOv[0][mt] = __builtin_amdgcn_mfma_f32_16x16x32_bf16(vf, pf0,         \
                                                    accOv[0][mt], 0, 0, 0);     \
        accOv[1][mt] = __builtin_amdgcn_mfma_f32_16x16x32_bf16(vf, pf1,         \
                                                    accOv[1][mt], 0, 0, 0);     \
      }                                                                         \
    }                                                                           \
    __builtin_amdgcn_s_setprio(0);                                              \
  } while (0)

__global__ __launch_bounds__(256) void flash_kernel(
    const ushort* __restrict__ qb, const ushort* __restrict__ kb,
    const ushort* __restrict__ vtb, ushort* __restrict__ ob) {
  __shared__ ushort Ks2[2][64][64];  // 16 KB  [buf][kv][hd] (swizzled chunks)
  __shared__ ushort Vs2[2][64][64];  // 16 KB  [buf][hd][kv] (swizzled chunks)
  __shared__ ushort Ps[4][32][64];   // 16 KB  per-wave P^T strip (swizzled)
  int tid = threadIdx.x;
  int wave = tid >> 6, lane = tid & 63, lrow = lane >> 4, lcol = lane & 15;

  int bid = blockIdx.x + (blockIdx.y << 3);  // grid (8,64) -> 0..511
  int xcd = bid & 7;                         // HW round-robin XCD id
  int slot = bid >> 3;                       // 0..63 per XCD
  int phase = slot >> 5;                     // slot s and s+32 -> same CU
  int j5 = slot & 31;
  int pm = j5 & 7;
  int bh = xcd * 8 + (j5 >> 3) + phase * 4;  // 8 bh per XCD -> K/V L2-resident
  int p = phase ? 7 - pm : pm;               // CU pair carries (p, 7-p): 50 units
  int qbA = 15 - p, qbB = p;
  int b = bh >> 4, h = bh & 15;
  const ushort* qp = qb + (size_t)bh * T_ * HD_;
  const ushort* kh = kb + (size_t)bh * T_ * HD_;
  const ushort* vh = vtb + (size_t)bh * HD_ * T_;

  int njA = 2 * qbA + 2, njB = 2 * qbB + 2;  // B's tiles are a prefix of A's

  int r0 = tid >> 3, dc = tid & 7;          // staging: row, 16B chunk
  int wsl = (dc ^ (r0 & 7)) * 8;            // swizzled slot (ushort offset)
  int rsw = lcol & 7;                       // read-side swizzle key

  uint4 kr0, kr1, vr0, vr1;                 // prefetch regs (one KV tile)
  auto gload = [&](int jt) {
    kr0 = *(const uint4*)&kh[(size_t)(jt * 64 + r0) * HD_ + dc * 8];
    kr1 = *(const uint4*)&kh[(size_t)(jt * 64 + r0 + 32) * HD_ + dc * 8];
    vr0 = *(const uint4*)&vh[(size_t)r0 * T_ + jt * 64 + dc * 8];
    vr1 = *(const uint4*)&vh[(size_t)(r0 + 32) * T_ + jt * 64 + dc * 8];
  };
  auto swrite = [&](int buf) {
    *(uint4*)&Ks2[buf][r0][wsl] = kr0;
    *(uint4*)&Ks2[buf][r0 + 32][wsl] = kr1;   // (r0+32)&7 == r0&7
    *(uint4*)&Vs2[buf][r0][wsl] = vr0;
    *(uint4*)&Vs2[buf][r0 + 32][wsl] = vr1;
  };

  // constant ones-row A-fragment: A[m=0][*]=1, A[m>0][*]=0 (m = lcol)
  bf16x8 af1;
  {
    __bf16 ov = (__bf16)((lcol == 0) ? 1.0f : 0.0f);
    for (int i2 = 0; i2 < 8; i2++) af1[i2] = ov;
  }

  f32x4 zero = {0.f, 0.f, 0.f, 0.f};

  // prologue: tile 0 -> buf0; prefetch tile 1
  gload(0);
  swrite(0);
  gload(1);
  __syncthreads();

  int q0wA = qbA * 128 + wave * 32, q0wB = qbB * 128 + wave * 32;
  bf16x8 qfA[2][2], qfB[2][2];
#pragma unroll
  for (int qh = 0; qh < 2; qh++)
#pragma unroll
    for (int ks = 0; ks < 2; ks++) {
      qfA[qh][ks] = *(const bf16x8*)&qp[(size_t)(q0wA + qh * 16 + lcol) * HD_ +
                                        ks * 32 + lrow * 8];
      qfB[qh][ks] = *(const bf16x8*)&qp[(size_t)(q0wB + qh * 16 + lcol) * HD_ +
                                        ks * 32 + lrow * 8];
    }

  f32x4 accOA[2][4], accOB[2][4];
  f32x4 accSA[2], accSB[2];
#pragma unroll
  for (int qh = 0; qh < 2; qh++) {
    accSA[qh] = zero; accSB[qh] = zero;
    for (int mt = 0; mt < 4; mt++) { accOA[qh][mt] = zero; accOB[qh][mt] = zero; }
  }

  for (int j = 0; j < njA; j++) {
    int cur = j & 1;
    if (j * 64 <= q0wA + 31) QCOMP(qbA, q0wA, qfA, accOA, accSA);
    if (j * 64 <= q0wB + 31) QCOMP(qbB, q0wB, qfB, accOB, accSB);
    // stage next tile (regs hold tile j+1) into the other buffer; its old
    // readers finished before the PREVIOUS barrier.
    if (j + 1 < njA) swrite(cur ^ 1);
    if (j + 2 < njA) gload(j + 2);
    __syncthreads();  // publish writes for next iteration
  }
  (void)njB;

  // epilogue per q-block / q-half
#pragma unroll
  for (int qh = 0; qh < 2; qh++) {
    float lsum = __shfl(accSA[qh][0], lcol);
    float linv = 1.f / lsum;
    int t = q0wA + qh * 16 + lcol;
    size_t base2 = ((size_t)b * T_ + t) * D_ + h * HD_;
#pragma unroll
    for (int mt = 0; mt < 4; mt++) {
      uint2 pk;
      pk.x = pkbf(accOA[qh][mt][0] * linv, accOA[qh][mt][1] * linv);
      pk.y = pkbf(accOA[qh][mt][2] * linv, accOA[qh][mt][3] * linv);
      *(uint2*)&ob[base2 + mt * 16 + lrow * 4] = pk;
    }
  }
#pragma unroll
  for (int qh = 0; qh < 2; qh++) {
    float lsum = __shfl(accSB[qh][0], lcol);
    float linv = 1.f / lsum;
    int t = q0wB + qh * 16 + lcol;
    size_t base2 = ((size_t)b * T_ + t) * D_ + h * HD_;
#pragma unroll
    for (int mt = 0; mt < 4; mt++) {
      uint2 pk;
      pk.x = pkbf(accOB[qh][mt][0] * linv, accOB[qh][mt][1] * linv);
      pk.y = pkbf(accOB[qh][mt][2] * linv, accOB[qh][mt][3] * linv);
      *(uint2*)&ob[base2 + mt * 16 + lrow * 4] = pk;
    }
  }
}

extern "C" void kernel_launch(void* const* d_in, const int* in_sizes, int n_in,
                              void* d_out, int out_size, void* d_ws, size_t ws_size,
                              hipStream_t stream) {
  (void)in_sizes; (void)n_in; (void)out_size; (void)ws_size;
  const float* x  = (const float*)d_in[0];
  const float* wq = (const float*)d_in[1];
  const float* bq = (const float*)d_in[2];
  const float* wk = (const float*)d_in[3];
  const float* bk = (const float*)d_in[4];
  const float* wv = (const float*)d_in[5];
  const float* bv = (const float*)d_in[6];
  const float* wo = (const float*)d_in[7];
  const float* bo = (const float*)d_in[8];
  float* out = (float*)d_out;

  char* ws = (char*)d_ws;
  ushort* xb     = (ushort*)(ws);              // 16 MB  x as bf16 (M x K)
  ushort* wt_qkv = (ushort*)(ws + 16777216);   // 6 MB   [wq|wk|wv]^T (3072 x 1024)
  ushort* wt_o   = (ushort*)(ws + 23068672);   // 2 MB   wo^T
  ushort* qb     = (ushort*)(ws + 25165824);   // 16 MB  Q (B,H,T,HD), pre-scaled
  ushort* kb     = (ushort*)(ws + 41943040);   // 16 MB  K (B,H,T,HD)
  ushort* vtb    = (ushort*)(ws + 58720256);   // 16 MB  V (B,H,HD,T)
  ushort* ob     = (ushort*)(ws + 75497472);   // 16 MB  attn out (B,T,D)

  cast_x_kernel<<<8192, 256, 0, stream>>>(x, xb);
  transpose_w_kernel<<<dim3(32, 32, 4), 256, 0, stream>>>(wq, wk, wv, wo, wt_qkv, wt_o);
  gemm_kernel<<<dim3(24, 64), 256, 0, stream>>>(xb, wt_qkv, 0, bq, bk, bv, qb, kb, vtb, nullptr);
  flash_kernel<<<dim3(8, 64), 256, 0, stream>>>(qb, kb, vtb, ob);
  gemm_kernel<<<dim3(8, 64), 256, 0, stream>>>(ob, wt_o, 1, bo, nullptr, nullptr,
                                               nullptr, nullptr, nullptr, out);
}